// Round 5
// baseline (455.213 us; speedup 1.0000x reference)
//
#include <hip/hip_runtime.h>

constexpr int H  = 16;
constexpr int HD = 48;
constexpr int D  = 768;    // H*HD
constexpr int DZ = 128;
constexpr int S  = 1024;
constexpr float EPS = 1e-5f;

__device__ __forceinline__ float sigmoidf_(float x) { return 1.f / (1.f + __expf(-x)); }

// ---------------------------------------------------------------------------
// Tiled f32 GEMM body: C[m][n] = sum_k A[m][k] * W[n][k]  (+bias[n], A gated by
// sigmoid(G) if G != nullptr). BM=BN=64, BK=16, 256 threads, 4x4 micro-tile.
// ---------------------------------------------------------------------------
__device__ __forceinline__ void gemm_tile(const float* __restrict__ A,
                                          const float* __restrict__ G,
                                          const float* __restrict__ W,
                                          const float* __restrict__ bias,
                                          float* __restrict__ C,
                                          const int bm, const int bn,
                                          const int N, const int K) {
  __shared__ float As[16][68];   // [k][m], row stride 68 floats (16B-aligned rows)
  __shared__ float Bs[16][68];   // [k][n]
  const int tid = threadIdx.x;
  const int tx = tid & 15, ty = tid >> 4;
  const int lr = tid >> 2;          // 0..63 tile row
  const int lk = (tid & 3) << 2;    // 0,4,8,12
  float acc[4][4] = {};
  for (int k0 = 0; k0 < K; k0 += 16) {
    float4 a = *reinterpret_cast<const float4*>(A + (size_t)(bm + lr) * K + (k0 + lk));
    if (G) {
      const float4 g = *reinterpret_cast<const float4*>(G + (size_t)(bm + lr) * K + (k0 + lk));
      a.x *= sigmoidf_(g.x); a.y *= sigmoidf_(g.y);
      a.z *= sigmoidf_(g.z); a.w *= sigmoidf_(g.w);
    }
    const float4 b = *reinterpret_cast<const float4*>(W + (size_t)(bn + lr) * K + (k0 + lk));
    As[lk + 0][lr] = a.x; As[lk + 1][lr] = a.y; As[lk + 2][lr] = a.z; As[lk + 3][lr] = a.w;
    Bs[lk + 0][lr] = b.x; Bs[lk + 1][lr] = b.y; Bs[lk + 2][lr] = b.z; Bs[lk + 3][lr] = b.w;
    __syncthreads();
#pragma unroll
    for (int k = 0; k < 16; ++k) {
      const float4 av = *reinterpret_cast<const float4*>(&As[k][ty << 2]);
      const float4 bv = *reinterpret_cast<const float4*>(&Bs[k][tx << 2]);
      const float am[4] = {av.x, av.y, av.z, av.w};
      const float bb[4] = {bv.x, bv.y, bv.z, bv.w};
#pragma unroll
      for (int i = 0; i < 4; ++i)
#pragma unroll
        for (int j = 0; j < 4; ++j) acc[i][j] += am[i] * bb[j];
    }
    __syncthreads();
  }
  float4 badd = make_float4(0.f, 0.f, 0.f, 0.f);
  if (bias) badd = *reinterpret_cast<const float4*>(bias + bn + (tx << 2));
#pragma unroll
  for (int i = 0; i < 4; ++i) {
    const int m = bm + (ty << 2) + i;
    float4 r;
    r.x = acc[i][0] + badd.x; r.y = acc[i][1] + badd.y;
    r.z = acc[i][2] + badd.z; r.w = acc[i][3] + badd.w;
    *reinterpret_cast<float4*>(C + (size_t)m * N + bn + (tx << 2)) = r;
  }
}

// Fused q/k/v/g projection: grid.x selects weight (4 x D/64), grid.y = S/64.
__global__ __launch_bounds__(256)
void qkvg_kernel(const float* __restrict__ s, const float* __restrict__ Wq,
                 const float* __restrict__ bq, const float* __restrict__ Wk,
                 const float* __restrict__ Wv, const float* __restrict__ Wg,
                 float* __restrict__ out) {
  const int nb = D / 64;
  const int wsel = blockIdx.x / nb;
  const int bn = (blockIdx.x % nb) * 64;
  const int bm = blockIdx.y * 64;
  const float* W = (wsel == 0) ? Wq : (wsel == 1) ? Wk : (wsel == 2) ? Wv : Wg;
  const float* bias = (wsel == 0) ? bq : nullptr;
  float* C = out + (size_t)wsel * S * D;
  gemm_tile(s, nullptr, W, bias, C, bm, bn, D, D);
}

// Gated output projection: out = (o * sigmoid(g)) @ Wo^T
__global__ __launch_bounds__(256)
void outproj_kernel(const float* __restrict__ o, const float* __restrict__ g,
                    const float* __restrict__ Wo, float* __restrict__ out) {
  gemm_tile(o, g, Wo, nullptr, out, blockIdx.y * 64, blockIdx.x * 64, D, D);
}

// ---------------------------------------------------------------------------
// pair-bias prep: WzW[h][c] = Wz[h][c]*ln_w[c]; S1[h] = sum_c WzW; S2[h] =
// sum_c ln_b[c]*Wz[h][c].  One small block.
// ---------------------------------------------------------------------------
__global__ __launch_bounds__(256)
void pb_prep_kernel(const float* __restrict__ Wz, const float* __restrict__ ln_w,
                    const float* __restrict__ ln_b, float* __restrict__ wzw,
                    float* __restrict__ s12) {
  const int t = threadIdx.x;
  for (int e = t; e < 16 * DZ; e += 256) wzw[e] = Wz[e] * ln_w[e & 127];
  if (t < 32) {
    const int h = t & 15;
    const float* coef = (t < 16) ? ln_w : ln_b;
    float a = 0.f;
    for (int c = 0; c < DZ; ++c) a += Wz[h * DZ + c] * coef[c];
    s12[t] = a;
  }
}

// ---------------------------------------------------------------------------
// Pair bias v4: wave-autonomous 8-row chunks with LDS corner-turn.
//  - load phase: lane reads 64B contiguous (4 float4) -> coalesced wave access
//    (8 cache lines per instr, vs 64 in v3's stride-512 pattern).
//  - row stats (s1,s2) computed in load phase + 3 shfl_xor within 8-lane
//    groups; mu/inv passed to compute roles via tiny LDS slot.
//  - corner-turn: wave-private LDS [8][132] (pad -> staging writes 2-way-free,
//    compute reads = 8 distinct 16B clusters on 32 banks, 8-lane broadcast).
//  - compute: lane owns (row r = lane&7, heads 2g,2g+1 with g = lane>>3);
//    weights broadcast from padded LDS copy. No barriers in the loop; next
//    chunk's global loads issued before compute (prefetch).
// ---------------------------------------------------------------------------
__global__ __launch_bounds__(256)
void pair_bias_kernel(const float* __restrict__ z, const float* __restrict__ wzw,
                      const float* __restrict__ s12, float* __restrict__ bias_out) {
  __shared__ float wlds[16 * 132];     // padded weights, 8.25 KB
  __shared__ float zs[4][8 * 132];     // per-wave staging, 4.2 KB each
  __shared__ float muinv[4][8][2];
  const int tid = threadIdx.x;
  for (int e = tid; e < 16 * DZ; e += 256)
    wlds[(e >> 7) * 132 + (e & 127)] = wzw[e];
  __syncthreads();   // only barrier in the kernel

  const int lane = tid & 63;
  const int wv = tid >> 6;
  float* Z = zs[wv];

  const int g = lane >> 3;       // head-pair group: h = 2g, 2g+1
  const int r = lane & 7;        // compute row within chunk
  const int lrow = lane >> 3;    // load row (lane's 64B = row lane>>3)
  const int lcb = lane & 7;      // load col-block (16 floats)

  const float S1a = s12[2 * g],     S2a = s12[16 + 2 * g];
  const float S1b = s12[2 * g + 1], S2b = s12[16 + 2 * g + 1];

  const int wave_id = blockIdx.x * 4 + wv;
  const int nwaves = gridDim.x * 4;          // 8192
  const int nchunks = (S * S) / 8;           // 131072 -> 16 iter/wave

  int chunk = wave_id;
  {
    const float* zp = z + (size_t)chunk * (8 * DZ) + lane * 16;
    // prologue handled by first loop iteration's "c" regs:
    // load chunk0 now
    // (kept in c0..c3 below)
    (void)zp;
  }
  const float* zp0 = z + (size_t)chunk * (8 * DZ) + lane * 16;
  float4 c0 = *reinterpret_cast<const float4*>(zp0 + 0);
  float4 c1 = *reinterpret_cast<const float4*>(zp0 + 4);
  float4 c2 = *reinterpret_cast<const float4*>(zp0 + 8);
  float4 c3 = *reinterpret_cast<const float4*>(zp0 + 12);

  for (; chunk < nchunks; chunk += nwaves) {
    // prefetch next chunk (clamped on last iteration)
    const int next = chunk + nwaves;
    const float* znp =
        z + (size_t)(next < nchunks ? next : chunk) * (8 * DZ) + lane * 16;
    const float4 n0 = *reinterpret_cast<const float4*>(znp + 0);
    const float4 n1 = *reinterpret_cast<const float4*>(znp + 4);
    const float4 n2 = *reinterpret_cast<const float4*>(znp + 8);
    const float4 n3 = *reinterpret_cast<const float4*>(znp + 12);

    // row stats for load-row (16 values per lane, reduce over 8-lane group)
    float s1 = (c0.x + c0.y + c0.z + c0.w) + (c1.x + c1.y + c1.z + c1.w) +
               (c2.x + c2.y + c2.z + c2.w) + (c3.x + c3.y + c3.z + c3.w);
    float s2 = c0.x * c0.x + c0.y * c0.y + c0.z * c0.z + c0.w * c0.w;
    s2 = fmaf(c1.x, c1.x, fmaf(c1.y, c1.y, fmaf(c1.z, c1.z, fmaf(c1.w, c1.w, s2))));
    s2 = fmaf(c2.x, c2.x, fmaf(c2.y, c2.y, fmaf(c2.z, c2.z, fmaf(c2.w, c2.w, s2))));
    s2 = fmaf(c3.x, c3.x, fmaf(c3.y, c3.y, fmaf(c3.z, c3.z, fmaf(c3.w, c3.w, s2))));
#pragma unroll
    for (int msk = 1; msk <= 4; msk <<= 1) {
      s1 += __shfl_xor(s1, msk);
      s2 += __shfl_xor(s2, msk);
    }
    const float mu = s1 * (1.f / DZ);
    const float inv = rsqrtf(s2 * (1.f / DZ) - mu * mu + EPS);
    if (lcb == 0) { muinv[wv][lrow][0] = mu; muinv[wv][lrow][1] = inv; }

    // stage current chunk into wave-private LDS (row stride 132 floats)
    float* zw = &Z[lrow * 132 + lcb * 16];
    *reinterpret_cast<float4*>(zw + 0) = c0;
    *reinterpret_cast<float4*>(zw + 4) = c1;
    *reinterpret_cast<float4*>(zw + 8) = c2;
    *reinterpret_cast<float4*>(zw + 12) = c3;

    // compute: lane -> (row r, heads 2g, 2g+1)
    float acca = 0.f, accb = 0.f;
#pragma unroll
    for (int j = 0; j < 32; ++j) {
      const float4 zq = *reinterpret_cast<const float4*>(&Z[r * 132 + 4 * j]);
      const float4 wa = *reinterpret_cast<const float4*>(&wlds[(2 * g) * 132 + 4 * j]);
      const float4 wb = *reinterpret_cast<const float4*>(&wlds[(2 * g + 1) * 132 + 4 * j]);
      acca += zq.x * wa.x + zq.y * wa.y + zq.z * wa.z + zq.w * wa.w;
      accb += zq.x * wb.x + zq.y * wb.y + zq.z * wb.z + zq.w * wb.w;
    }
    const float mur = muinv[wv][r][0];
    const float invr = muinv[wv][r][1];
    const size_t p = (size_t)chunk * 8 + r;
    bias_out[(size_t)(2 * g) * S * S + p] = invr * (acca - mur * S1a) + S2a;
    bias_out[(size_t)(2 * g + 1) * S * S + p] = invr * (accb - mur * S1b) + S2b;

    c0 = n0; c1 = n1; c2 = n2; c3 = n3;
  }
}

// ---------------------------------------------------------------------------
// Flash-style attention. Block = (head h, 64 query rows), 256 threads (16x16).
// ---------------------------------------------------------------------------
__global__ __launch_bounds__(256)
void attn_kernel(const float* __restrict__ q_ws, const float* __restrict__ k_ws,
                 const float* __restrict__ v_ws, const float* __restrict__ bias,
                 float* __restrict__ o_ws) {
  __shared__ float Qs[64][52];   // query rows (scaled), padded
  __shared__ float Ks[64][52];   // key rows, padded
  __shared__ float Vt[48][68];   // V transposed [d][t]
  __shared__ float Ps[64][68];   // probabilities tile

  const int tid = threadIdx.x;
  const int tx = tid & 15, ty = tid >> 4;
  const int h  = blockIdx.x >> 4;
  const int q0 = (blockIdx.x & 15) << 6;
  const float scale = 0.14433756729740643f;  // 1/sqrt(48)

  // stage Q (scaled): 64 rows x 12 float4
#pragma unroll
  for (int i = 0; i < 3; ++i) {
    const int f4 = tid + i * 256;
    const int r = f4 / 12, c4 = f4 % 12;
    float4 v = *reinterpret_cast<const float4*>(q_ws + (size_t)(q0 + r) * D + h * HD + c4 * 4);
    v.x *= scale; v.y *= scale; v.z *= scale; v.w *= scale;
    *reinterpret_cast<float4*>(&Qs[r][c4 * 4]) = v;
  }

  float m[4], l[4] = {0.f, 0.f, 0.f, 0.f};
  float acc[4][3] = {};
#pragma unroll
  for (int i = 0; i < 4; ++i) m[i] = -1e30f;

  for (int t0 = 0; t0 < S; t0 += 64) {
    // stage K tile (rows) and V tile (transposed)
#pragma unroll
    for (int i = 0; i < 3; ++i) {
      const int f4 = tid + i * 256;
      const int r = f4 / 12, c4 = f4 % 12;
      const float4 kv = *reinterpret_cast<const float4*>(k_ws + (size_t)(t0 + r) * D + h * HD + c4 * 4);
      *reinterpret_cast<float4*>(&Ks[r][c4 * 4]) = kv;
      const float4 vv = *reinterpret_cast<const float4*>(v_ws + (size_t)(t0 + r) * D + h * HD + c4 * 4);
      Vt[c4 * 4 + 0][r] = vv.x; Vt[c4 * 4 + 1][r] = vv.y;
      Vt[c4 * 4 + 2][r] = vv.z; Vt[c4 * 4 + 3][r] = vv.w;
    }
    __syncthreads();

    // S-tile: rows 4ty+i, cols 4tx+j, init from bias
    float s4[4][4];
#pragma unroll
    for (int i = 0; i < 4; ++i) {
      const float4 b4 = *reinterpret_cast<const float4*>(
          bias + ((size_t)h * S + (q0 + 4 * ty + i)) * S + t0 + 4 * tx);
      s4[i][0] = b4.x; s4[i][1] = b4.y; s4[i][2] = b4.z; s4[i][3] = b4.w;
    }
#pragma unroll
    for (int k4 = 0; k4 < 12; ++k4) {
      float4 qv[4], kv[4];
#pragma unroll
      for (int i = 0; i < 4; ++i) qv[i] = *reinterpret_cast<const float4*>(&Qs[4 * ty + i][k4 * 4]);
#pragma unroll
      for (int j = 0; j < 4; ++j) kv[j] = *reinterpret_cast<const float4*>(&Ks[4 * tx + j][k4 * 4]);
#pragma unroll
      for (int i = 0; i < 4; ++i)
#pragma unroll
        for (int j = 0; j < 4; ++j)
          s4[i][j] += qv[i].x * kv[j].x + qv[i].y * kv[j].y +
                      qv[i].z * kv[j].z + qv[i].w * kv[j].w;
    }

    // online softmax (row groups = 16 tx lanes; shfl_xor stays in-group)
#pragma unroll
    for (int i = 0; i < 4; ++i) {
      float tmax = fmaxf(fmaxf(s4[i][0], s4[i][1]), fmaxf(s4[i][2], s4[i][3]));
#pragma unroll
      for (int off = 8; off >= 1; off >>= 1) tmax = fmaxf(tmax, __shfl_xor(tmax, off));
      const float mn = fmaxf(m[i], tmax);
      const float fac = __expf(m[i] - mn);
      float p0 = __expf(s4[i][0] - mn), p1 = __expf(s4[i][1] - mn);
      float p2 = __expf(s4[i][2] - mn), p3 = __expf(s4[i][3] - mn);
      l[i] = l[i] * fac + (p0 + p1 + p2 + p3);   // per-thread partial sum
      acc[i][0] *= fac; acc[i][1] *= fac; acc[i][2] *= fac;
      m[i] = mn;
      *reinterpret_cast<float4*>(&Ps[4 * ty + i][4 * tx]) = make_float4(p0, p1, p2, p3);
    }
    __syncthreads();

    // PV: rows 4ty+i, dims 3tx+j, vectorized over t-quads
#pragma unroll
    for (int t4 = 0; t4 < 16; ++t4) {
      float4 pv[4], vv[3];
#pragma unroll
      for (int i = 0; i < 4; ++i) pv[i] = *reinterpret_cast<const float4*>(&Ps[4 * ty + i][4 * t4]);
#pragma unroll
      for (int j = 0; j < 3; ++j) vv[j] = *reinterpret_cast<const float4*>(&Vt[3 * tx + j][4 * t4]);
#pragma unroll
      for (int i = 0; i < 4; ++i)
#pragma unroll
        for (int j = 0; j < 3; ++j)
          acc[i][j] += pv[i].x * vv[j].x + pv[i].y * vv[j].y +
                       pv[i].z * vv[j].z + pv[i].w * vv[j].w;
    }
    __syncthreads();
  }

  // finalize: full row sum of l across tx group, normalize, write
#pragma unroll
  for (int i = 0; i < 4; ++i) {
    float lt = l[i];
#pragma unroll
    for (int off = 8; off >= 1; off >>= 1) lt += __shfl_xor(lt, off);
    const float rl = 1.f / lt;
    float* op = o_ws + (size_t)(q0 + 4 * ty + i) * D + h * HD;
#pragma unroll
    for (int j = 0; j < 3; ++j) op[3 * tx + j] = acc[i][j] * rl;
  }
}

extern "C" void kernel_launch(void* const* d_in, const int* in_sizes, int n_in,
                              void* d_out, int out_size, void* d_ws, size_t ws_size,
                              hipStream_t stream) {
  const float* s    = (const float*)d_in[0];
  const float* z    = (const float*)d_in[1];
  const float* Wq   = (const float*)d_in[2];
  const float* bq   = (const float*)d_in[3];
  const float* Wk   = (const float*)d_in[4];
  const float* Wv   = (const float*)d_in[5];
  const float* Wg   = (const float*)d_in[6];
  const float* ln_w = (const float*)d_in[7];
  const float* ln_b = (const float*)d_in[8];
  const float* Wz   = (const float*)d_in[9];
  const float* Wo   = (const float*)d_in[10];
  float* out = (float*)d_out;

  // workspace (floats): q,k,v,g,o = 5*S*D; bias = H*S*S; wzw = 2048; s12 = 32
  float* q_ws    = (float*)d_ws;
  float* k_ws    = q_ws + (size_t)S * D;
  float* v_ws    = k_ws + (size_t)S * D;
  float* g_ws    = v_ws + (size_t)S * D;
  float* o_ws    = g_ws + (size_t)S * D;
  float* bias_ws = o_ws + (size_t)S * D;
  float* wzw_ws  = bias_ws + (size_t)H * S * S;
  float* s12_ws  = wzw_ws + 16 * DZ;

  // 1) fused QKVG projections
  qkvg_kernel<<<dim3(4 * (D / 64), S / 64), 256, 0, stream>>>(s, Wq, bq, Wk, Wv, Wg, q_ws);
  // 2) pair bias (LN folded): prep then streaming kernel
  pb_prep_kernel<<<1, 256, 0, stream>>>(Wz, ln_w, ln_b, wzw_ws, s12_ws);
  pair_bias_kernel<<<2048, 256, 0, stream>>>(z, wzw_ws, s12_ws, bias_ws);
  // 3) flash attention
  attn_kernel<<<dim3(H * (S / 64)), 256, 0, stream>>>(q_ws, k_ws, v_ws, bias_ws, o_ws);
  // 4) gate + output projection
  outproj_kernel<<<dim3(D / 64, S / 64), 256, 0, stream>>>(o_ws, g_ws, Wo, out);
}